// Round 8
// baseline (906.700 us; speedup 1.0000x reference)
//
#include <hip/hip_runtime.h>
#include <stdint.h>

#define LQ 2048
#define EDIM 1024
#define HN 8
#define DH 128
#define BATCH 4
#define SCALE_LOG2E 0.12753785051263942f  // (1/sqrt(128)) * log2(e)

typedef short bf16x8 __attribute__((ext_vector_type(8)));
typedef float f32x4 __attribute__((ext_vector_type(4)));
typedef unsigned short u16;
typedef unsigned short u16x4 __attribute__((ext_vector_type(4)));

__device__ __forceinline__ u16 f2bf(float f) {
  union { float f; uint32_t u; } c; c.f = f;
  uint32_t u = c.u;
  return (u16)((u + 0x7fffu + ((u >> 16) & 1u)) >> 16);
}

__device__ __forceinline__ void async16(const void* g, void* l) {
  __builtin_amdgcn_global_load_lds((const __attribute__((address_space(1))) void*)g,
                                   (__attribute__((address_space(3))) void*)l, 16, 0, 0);
}

// LDS byte address for inline-asm DS ops
__device__ __forceinline__ uint32_t lds_b(const u16* p) {
  return (uint32_t)(uintptr_t)(__attribute__((address_space(3))) const u16*)p;
}
// Multi-read asm blocks MUST use early-clobber outputs (R6 lesson).
__device__ __forceinline__ void ldsr4(bf16x8& d0, bf16x8& d1, bf16x8& d2, bf16x8& d3,
                                      uint32_t a0, uint32_t a1, uint32_t a2, uint32_t a3) {
  asm volatile("ds_read_b128 %0, %4\n\t"
               "ds_read_b128 %1, %5\n\t"
               "ds_read_b128 %2, %6\n\t"
               "ds_read_b128 %3, %7\n\t"
               "s_waitcnt lgkmcnt(0)"
               : "=&v"(d0), "=&v"(d1), "=&v"(d2), "=&v"(d3)
               : "v"(a0), "v"(a1), "v"(a2), "v"(a3));
}
__device__ __forceinline__ void ldsr2(bf16x8& d0, bf16x8& d1, uint32_t a0, uint32_t a1) {
  asm volatile("ds_read_b128 %0, %2\n\t"
               "ds_read_b128 %1, %3\n\t"
               "s_waitcnt lgkmcnt(0)"
               : "=&v"(d0), "=&v"(d1) : "v"(a0), "v"(a1));
}
__device__ __forceinline__ void ldsr1(bf16x8& d0, uint32_t a0) {
  asm volatile("ds_read_b128 %0, %1\n\t"
               "s_waitcnt lgkmcnt(0)"
               : "=&v"(d0) : "v"(a0));
}
__device__ __forceinline__ void ldsw16(uint32_t a, u16 v) {
  asm volatile("ds_write_b16 %0, %1" :: "v"(a), "v"((uint32_t)v));
}
__device__ __forceinline__ void lgkm_drain() {
  asm volatile("s_waitcnt lgkmcnt(0)" ::: "memory");
}

// ---------------- fused prep: cvt inputs + transpose weights + mask tile scan ----------------
__global__ __launch_bounds__(256) void prep_kernel(const float* __restrict__ qIn, const float* __restrict__ kvIn,
                                                   const float* __restrict__ w0, const float* __restrict__ w1,
                                                   const float* __restrict__ w2, const float* __restrict__ w3,
                                                   const unsigned char* __restrict__ mask,
                                                   u16* __restrict__ oq, u16* __restrict__ okv,
                                                   u16* __restrict__ o0, u16* __restrict__ o1,
                                                   u16* __restrict__ o2, u16* __restrict__ o3,
                                                   unsigned char* __restrict__ flags) {
  __shared__ float tile[32][33];
  __shared__ int wany[4];
  const int bid = blockIdx.x;
  const int t = threadIdx.x;
  if (bid < 16384) {
    const float* in = (bid >= 8192) ? kvIn : qIn;
    u16* out = (bid >= 8192) ? okv : oq;
    size_t i = (size_t)(bid & 8191) * 256 + t;
    float4 v = ((const float4*)in)[i];
    u16x4 o;
    o.x = f2bf(v.x); o.y = f2bf(v.y); o.z = f2bf(v.z); o.w = f2bf(v.w);
    ((u16x4*)out)[i] = o;
  } else if (bid < 20480) {
    const int idx = bid - 16384;
    const int z = idx >> 10;
    const int rem = idx & 1023;
    const float* in; u16* out;
    switch (z) {
      case 0: in = w0; out = o0; break;
      case 1: in = w1; out = o1; break;
      case 2: in = w2; out = o2; break;
      default: in = w3; out = o3; break;
    }
    const int tx = t & 31, ty = t >> 5;
    const int x0 = (rem & 31) * 32;
    const int y0 = (rem >> 5) * 32;
#pragma unroll
    for (int j = 0; j < 32; j += 8)
      tile[ty + j][tx] = in[(size_t)(y0 + ty + j) * EDIM + x0 + tx];
    __syncthreads();
#pragma unroll
    for (int j = 0; j < 32; j += 8)
      out[(size_t)(x0 + ty + j) * EDIM + (y0 + tx)] = f2bf(tile[tx][ty + j]);
  } else {
    const int idx = bid - 20480;
    const int bh = idx >> 8;
    const int tile16 = idx & 255;
    const int qt = tile16 >> 4, kt = tile16 & 15;
    const int r = t >> 1;
    const size_t base = ((size_t)bh * LQ + qt * 128 + r) * LQ + kt * 128 + (t & 1) * 64;
    const uint4* p = (const uint4*)(mask + base);
    uint4 a = p[0], c = p[1], d = p[2], e = p[3];
    uint32_t any = a.x | a.y | a.z | a.w | c.x | c.y | c.z | c.w |
                   d.x | d.y | d.z | d.w | e.x | e.y | e.z | e.w;
    int wa = __any(any != 0);
    if ((t & 63) == 0) wany[t >> 6] = wa;
    __syncthreads();
    if (t == 0)
      flags[(size_t)bh * 256 + tile16] = (unsigned char)(wany[0] | wany[1] | wany[2] | wany[3]);
  }
}

// ---------------- BK=64 GEMM core (XOR-swizzled LDS, 128x128 tile) ----------------
struct GemmCore {
  template <typename EpiF>
  static __device__ __forceinline__ void run(const u16* __restrict__ A, const u16* __restrict__ Bt,
                                             int m0, int n0, u16* As, u16* Bs, EpiF epi) {
    const int tid = threadIdx.x;
    const int l = tid & 63;
    const int w = tid >> 6;
    const int wm = (w >> 1) * 64;
    const int wn = (w & 1) * 64;
    const int fm = l & 15;
    const int q4 = l >> 4;
    const int f7 = fm & 7;
    f32x4 acc[4][4] = {};
    for (int k0 = 0; k0 < EDIM; k0 += 64) {
      __syncthreads();
#pragma unroll
      for (int ii = 0; ii < 4; ++ii) {
        const int rloc = w * 32 + ii * 8 + (l >> 3);
        const int cs = (l & 7) ^ (rloc & 7);
        async16(A + (size_t)(m0 + rloc) * EDIM + k0 + cs * 8, &As[(w * 32 + ii * 8) * 64 + l * 8]);
        async16(Bt + (size_t)(n0 + rloc) * EDIM + k0 + cs * 8, &Bs[(w * 32 + ii * 8) * 64 + l * 8]);
      }
      __syncthreads();
#pragma unroll
      for (int ks = 0; ks < 2; ++ks) {
        const int coff = ((ks * 4 + q4) ^ f7) * 8;
        bf16x8 a[4], b[4];
#pragma unroll
        for (int i = 0; i < 4; ++i) a[i] = *(const bf16x8*)&As[(wm + i * 16 + fm) * 64 + coff];
#pragma unroll
        for (int j = 0; j < 4; ++j) b[j] = *(const bf16x8*)&Bs[(wn + j * 16 + fm) * 64 + coff];
#pragma unroll
        for (int i = 0; i < 4; ++i)
#pragma unroll
          for (int j = 0; j < 4; ++j)
            acc[i][j] = __builtin_amdgcn_mfma_f32_16x16x32_bf16(a[i], b[j], acc[i][j], 0, 0, 0);
      }
    }
    const int rr = q4 * 4;
#pragma unroll
    for (int i = 0; i < 4; ++i)
#pragma unroll
      for (int j = 0; j < 4; ++j)
#pragma unroll
        for (int r = 0; r < 4; ++r)
          epi(m0 + wm + i * 16 + rr + r, n0 + wn + j * 16 + fm, acc[i][j][r]);
  }
};

__global__ __launch_bounds__(256) void qkv_gemm(const u16* __restrict__ xq, const u16* __restrict__ xkv,
                                                const u16* __restrict__ WqT, const u16* __restrict__ WkT,
                                                const u16* __restrict__ WvT,
                                                u16* __restrict__ Qb, u16* __restrict__ Kb,
                                                u16* __restrict__ Vt) {
  __shared__ __align__(16) u16 As[128 * 64];
  __shared__ __align__(16) u16 Bs[128 * 64];
  const int z = blockIdx.z;
  if (z == 0) {
    GemmCore::run(xq, WqT, blockIdx.x * 128, blockIdx.y * 128, As, Bs,
                  [&](int gm, int gn, float v) { Qb[(size_t)gm * EDIM + gn] = f2bf(v); });
  } else if (z == 1) {
    GemmCore::run(xkv, WkT, blockIdx.x * 128, blockIdx.y * 128, As, Bs,
                  [&](int gm, int gn, float v) { Kb[(size_t)gm * EDIM + gn] = f2bf(v); });
  } else {
    GemmCore::run(WvT, xkv, blockIdx.y * 128, blockIdx.x * 128, As, Bs,
                  [&](int gm, int gn, float v) {
                    Vt[((size_t)(gn >> 11) * 1024 + gm) * 2048 + (gn & 2047)] = f2bf(v);
                  });
  }
}

__global__ __launch_bounds__(256) void out_gemm(const u16* __restrict__ ctx, const u16* __restrict__ WfcT,
                                                float* __restrict__ out) {
  __shared__ __align__(16) u16 As[128 * 64];
  __shared__ __align__(16) u16 Bs[128 * 64];
  GemmCore::run(ctx, WfcT, blockIdx.x * 128, blockIdx.y * 128, As, Bs,
                [&](int gm, int gn, float v) { out[(size_t)gm * EDIM + gn] = v; });
}

// ---------------- flash attention v4: 64-q blocks, BN=32, dbuf K/V, 4 blocks/CU ----------------
// grid (qtile=32, h=8, b=4) = 1024 blocks = exactly 4/CU; 4 waves x 16 q-rows each.
// LDS 36 KB/block; __launch_bounds__(256,4) caps VGPR at 128 -> 16 waves/CU (2x v3).
// 1 barrier/iter; prefetch of iter t+1 in flight across iter t's compute.
__global__ __launch_bounds__(256, 4) void attn_kernel(const u16* __restrict__ Qb, const u16* __restrict__ Kb,
                                                      const u16* __restrict__ Vt,
                                                      const unsigned char* __restrict__ mask,
                                                      const unsigned char* __restrict__ flags,
                                                      u16* __restrict__ ctx) {
  __shared__ __align__(16) u16 Ktile[2][32 * 128];   // [key][d], 256B rows = 16 chunks, XOR-swz
  __shared__ __align__(16) u16 Vtile[2][128 * 32];   // [d][key], 64B rows = 4 chunks, XOR-swz
  __shared__ __align__(16) u16 P[4 * 16 * 32];       // wave-private [16 q][32 key], XOR-swz
  const int tid = threadIdx.x;
  const int l = tid & 63;
  const int w = tid >> 6;
  const int qt = blockIdx.x;
  const int h = blockIdx.y;
  const int b = blockIdx.z;
  const int fm = l & 15;
  const int q4 = l >> 4;
  const int fk = q4 * 8;
  const int f7 = fm & 7;
  const int qbase = qt * 64 + w * 16;
  const int bh = b * HN + h;
  u16* Pw = &P[w * 512];

  const u16* Kbh = Kb + (size_t)b * LQ * EDIM + h * DH;
  const u16* Vth = Vt + (size_t)bh * DH * LQ;
  const size_t mbase = (size_t)bh * (size_t)LQ * LQ;

  // per-qtile mask flags (128-key granularity); qtile covers q rows qt*64..qt*64+63
  // -> flag row index = (qt*64)/128 = qt>>1
  const unsigned char* tf = flags + (size_t)bh * 256 + (qt >> 1) * 16;
  uint32_t fmask = 0;
#pragma unroll
  for (int i = 0; i < 16; ++i) fmask |= (tf[i] ? 1u : 0u) << i;

  // Q fragments: A-layout, lane holds Q[m=fm][k=q4*8+j]; 16 rows per wave
  bf16x8 qf[4];
#pragma unroll
  for (int ks = 0; ks < 4; ++ks)
    qf[ks] = *(const bf16x8*)(Qb + (size_t)(b * LQ + qbase + fm) * EDIM + h * DH + ks * 32 + fk);

  // staging: K 8KB/buffer (8 instrs), V 8KB/buffer (8 instrs) -> 2+2 per wave
  auto stageK = [&](int kt_, int buf) {
#pragma unroll
    for (int ii = 0; ii < 2; ++ii) {
      const int i = w * 2 + ii;
      const int row = i * 4 + (l >> 4);          // key row 0..31
      const int g = (l & 15) ^ (row & 7);
      async16(Kbh + (size_t)(kt_ * 32 + row) * EDIM + g * 8, &Ktile[buf][i * 512 + l * 8]);
    }
  };
  auto stageV = [&](int kt_, int buf) {
#pragma unroll
    for (int ii = 0; ii < 2; ++ii) {
      const int i = w * 2 + ii;
      const int row = i * 16 + (l >> 2);         // d row 0..127
      const int g = (l & 3) ^ (row & 3);
      async16(Vth + (size_t)row * LQ + kt_ * 32 + g * 8, &Vtile[buf][i * 512 + l * 8]);
    }
  };

  stageK(0, 0);
  stageV(0, 0);

  f32x4 o[8] = {};
  float lsum[4] = {};

  for (int kt = 0; kt < 64; ++kt) {
    const int cur = kt & 1;
    __syncthreads();  // drains own DMA (issued a full iter ago) + all waves done with other buffer
    if (kt + 1 < 64) { stageK(kt + 1, 1 - cur); stageV(kt + 1, 1 - cur); }

    const u16* KT = &Ktile[cur][0];
    const u16* VT = &Vtile[cur][0];

    // ---- S = Q K^T (32 keys = 2 n-tiles)
    f32x4 s[2] = {};
#pragma unroll
    for (int ks = 0; ks < 4; ++ks) {
      const int slot = (ks * 4 + q4) ^ f7;
      bf16x8 kf0, kf1;
      ldsr2(kf0, kf1,
            lds_b(KT + (0 * 16 + fm) * 128 + slot * 8),
            lds_b(KT + (1 * 16 + fm) * 128 + slot * 8));
      s[0] = __builtin_amdgcn_mfma_f32_16x16x32_bf16(qf[ks], kf0, s[0], 0, 0, 0);
      s[1] = __builtin_amdgcn_mfma_f32_16x16x32_bf16(qf[ks], kf1, s[1], 0, 0, 0);
    }

    // ---- softmax (no max-subtraction; masked -> 0)
    const int hasMask = (fmask >> (kt >> 2)) & 1;
#pragma unroll
    for (int r = 0; r < 4; ++r) {
      float sum = 0.f;
      if (hasMask) {
        const int qr = qbase + q4 * 4 + r;
        const unsigned char* mrow = mask + mbase + (size_t)qr * LQ + kt * 32 + fm;
#pragma unroll
        for (int nt = 0; nt < 2; ++nt) {
          float e = mrow[nt * 16] ? 0.f : exp2f(s[nt][r] * SCALE_LOG2E);
          s[nt][r] = e;
          sum += e;
        }
      } else {
#pragma unroll
        for (int nt = 0; nt < 2; ++nt) {
          float e = exp2f(s[nt][r] * SCALE_LOG2E);
          s[nt][r] = e;
          sum += e;
        }
      }
#pragma unroll
      for (int off = 1; off < 16; off <<= 1) sum += __shfl_xor(sum, off);
      lsum[r] += sum;
    }

    // ---- P to wave-private LDS. slot = chunk ^ (ql&3) ^ ((ql>>2)&3): spreads q4 across banks.
#pragma unroll
    for (int r = 0; r < 4; ++r) {
      const int ql = q4 * 4 + r;
      const int sw = (ql & 3) ^ ((ql >> 2) & 3);
#pragma unroll
      for (int nt = 0; nt < 2; ++nt) {
        const int chunk = nt * 2 + (fm >> 3);
        ldsw16(lds_b(Pw + ql * 32 + (chunk ^ sw) * 8 + (fm & 7)), f2bf(s[nt][r]));
      }
    }
    lgkm_drain();  // P writes visible before P reads

    // ---- O += P V (K-dim 32 = one MFMA k-step; A-frag P row fm, k=q4*8..)
    {
      const int pslot = q4 ^ (fm & 3) ^ ((fm >> 2) & 3);
      bf16x8 pf;
      ldsr1(pf, lds_b(Pw + fm * 32 + pslot * 8));
#pragma unroll
      for (int dt = 0; dt < 8; dt += 2) {
        const int r0 = dt * 16 + fm, r1 = (dt + 1) * 16 + fm;
        bf16x8 v0, v1;
        ldsr2(v0, v1,
              lds_b(VT + r0 * 32 + (q4 ^ (r0 & 3)) * 8),
              lds_b(VT + r1 * 32 + (q4 ^ (r1 & 3)) * 8));
        o[dt]     = __builtin_amdgcn_mfma_f32_16x16x32_bf16(pf, v0, o[dt], 0, 0, 0);
        o[dt + 1] = __builtin_amdgcn_mfma_f32_16x16x32_bf16(pf, v1, o[dt + 1], 0, 0, 0);
      }
    }
  }

  // ---- epilogue: ctx = O / lsum
#pragma unroll
  for (int r = 0; r < 4; ++r) {
    float inv = 1.f / lsum[r];
    int gq = b * LQ + qbase + q4 * 4 + r;
#pragma unroll
    for (int dt = 0; dt < 8; ++dt)
      ctx[(size_t)gq * EDIM + h * DH + dt * 16 + fm] = f2bf(o[dt][r] * inv);
  }
}

extern "C" void kernel_launch(void* const* d_in, const int* in_sizes, int n_in,
                              void* d_out, int out_size, void* d_ws, size_t ws_size,
                              hipStream_t stream) {
  const float* qIn = (const float*)d_in[0];
  const float* kvIn = (const float*)d_in[1];
  const unsigned char* mask = (const unsigned char*)d_in[2];
  const float* W_Q = (const float*)d_in[3];
  const float* W_K = (const float*)d_in[4];
  const float* W_V = (const float*)d_in[5];
  const float* W_fc = (const float*)d_in[6];
  float* out = (float*)d_out;

  uint8_t* ws = (uint8_t*)d_ws;
  const size_t MB = 1u << 20;
  u16* xq   = (u16*)(ws);
  u16* xkv  = (u16*)(ws + 16 * MB);
  u16* WqT  = (u16*)(ws + 32 * MB);
  u16* WkT  = (u16*)(ws + 34 * MB);
  u16* WvT  = (u16*)(ws + 36 * MB);
  u16* WfcT = (u16*)(ws + 38 * MB);
  u16* Qb   = (u16*)(ws + 40 * MB);
  u16* Kb   = (u16*)(ws + 56 * MB);
  u16* Vt   = (u16*)(ws + 72 * MB);
  u16* ctx  = (u16*)(ws + 88 * MB);
  unsigned char* flags = (unsigned char*)(ws + 104 * MB);

  prep_kernel<<<28672, 256, 0, stream>>>(qIn, kvIn, W_Q, W_K, W_V, W_fc, mask,
                                         xq, xkv, WqT, WkT, WvT, WfcT, flags);
  qkv_gemm<<<dim3(64, 8, 3), 256, 0, stream>>>(xq, xkv, WqT, WkT, WvT, Qb, Kb, Vt);
  attn_kernel<<<dim3(32, 8, 4), 256, 0, stream>>>(Qb, Kb, Vt, mask, flags, ctx);
  out_gemm<<<dim3(64, 8), 256, 0, stream>>>(ctx, WfcT, out);
}

// Round 9
// 887.766 us; speedup vs baseline: 1.0213x; 1.0213x over previous
//
#include <hip/hip_runtime.h>
#include <hip/hip_bf16.h>
#include <stdint.h>

#define LQ 2048
#define EDIM 1024
#define HN 8
#define DH 128
#define BATCH 4
#define SCALE_LOG2E 0.12753785051263942f  // (1/sqrt(128)) * log2(e)

typedef short bf16x8 __attribute__((ext_vector_type(8)));
typedef float f32x4 __attribute__((ext_vector_type(4)));
typedef unsigned short u16;
typedef unsigned short u16x4 __attribute__((ext_vector_type(4)));

__device__ __forceinline__ u16 f2bf(float f) {
  union { float f; uint32_t u; } c; c.f = f;
  uint32_t u = c.u;
  return (u16)((u + 0x7fffu + ((u >> 16) & 1u)) >> 16);
}
// packed RNE cvt of two floats -> two bf16 (lo=a, hi=b)
__device__ __forceinline__ uint32_t pk2bf(float a, float b) {
  __hip_bfloat162 h = __float22bfloat162_rn(float2{a, b});
  union { __hip_bfloat162 h; uint32_t u; } c; c.h = h;
  return c.u;
}

__device__ __forceinline__ void async16(const void* g, void* l) {
  __builtin_amdgcn_global_load_lds((const __attribute__((address_space(1))) void*)g,
                                   (__attribute__((address_space(3))) void*)l, 16, 0, 0);
}

// LDS byte address for inline-asm DS ops
__device__ __forceinline__ uint32_t lds_b(const u16* p) {
  return (uint32_t)(uintptr_t)(__attribute__((address_space(3))) const u16*)p;
}
// Multi-read asm blocks MUST use early-clobber outputs (R6 lesson).
__device__ __forceinline__ void ldsr4(bf16x8& d0, bf16x8& d1, bf16x8& d2, bf16x8& d3,
                                      uint32_t a0, uint32_t a1, uint32_t a2, uint32_t a3) {
  asm volatile("ds_read_b128 %0, %4\n\t"
               "ds_read_b128 %1, %5\n\t"
               "ds_read_b128 %2, %6\n\t"
               "ds_read_b128 %3, %7\n\t"
               "s_waitcnt lgkmcnt(0)"
               : "=&v"(d0), "=&v"(d1), "=&v"(d2), "=&v"(d3)
               : "v"(a0), "v"(a1), "v"(a2), "v"(a3));
}
__device__ __forceinline__ void ldsr2(bf16x8& d0, bf16x8& d1, uint32_t a0, uint32_t a1) {
  asm volatile("ds_read_b128 %0, %2\n\t"
               "ds_read_b128 %1, %3\n\t"
               "s_waitcnt lgkmcnt(0)"
               : "=&v"(d0), "=&v"(d1) : "v"(a0), "v"(a1));
}
__device__ __forceinline__ void ldsw16(uint32_t a, u16 v) {
  asm volatile("ds_write_b16 %0, %1" :: "v"(a), "v"((uint32_t)v));
}
__device__ __forceinline__ void lgkm_drain() {
  asm volatile("s_waitcnt lgkmcnt(0)" ::: "memory");
}

// ---------------- fused prep: cvt inputs + transpose weights + mask tile scan ----------------
__global__ __launch_bounds__(256) void prep_kernel(const float* __restrict__ qIn, const float* __restrict__ kvIn,
                                                   const float* __restrict__ w0, const float* __restrict__ w1,
                                                   const float* __restrict__ w2, const float* __restrict__ w3,
                                                   const unsigned char* __restrict__ mask,
                                                   u16* __restrict__ oq, u16* __restrict__ okv,
                                                   u16* __restrict__ o0, u16* __restrict__ o1,
                                                   u16* __restrict__ o2, u16* __restrict__ o3,
                                                   unsigned char* __restrict__ flags) {
  __shared__ float tile[32][33];
  __shared__ int wany[4];
  const int bid = blockIdx.x;
  const int t = threadIdx.x;
  if (bid < 16384) {
    const float* in = (bid >= 8192) ? kvIn : qIn;
    u16* out = (bid >= 8192) ? okv : oq;
    size_t i = (size_t)(bid & 8191) * 256 + t;
    float4 v = ((const float4*)in)[i];
    u16x4 o;
    o.x = f2bf(v.x); o.y = f2bf(v.y); o.z = f2bf(v.z); o.w = f2bf(v.w);
    ((u16x4*)out)[i] = o;
  } else if (bid < 20480) {
    const int idx = bid - 16384;
    const int z = idx >> 10;
    const int rem = idx & 1023;
    const float* in; u16* out;
    switch (z) {
      case 0: in = w0; out = o0; break;
      case 1: in = w1; out = o1; break;
      case 2: in = w2; out = o2; break;
      default: in = w3; out = o3; break;
    }
    const int tx = t & 31, ty = t >> 5;
    const int x0 = (rem & 31) * 32;
    const int y0 = (rem >> 5) * 32;
#pragma unroll
    for (int j = 0; j < 32; j += 8)
      tile[ty + j][tx] = in[(size_t)(y0 + ty + j) * EDIM + x0 + tx];
    __syncthreads();
#pragma unroll
    for (int j = 0; j < 32; j += 8)
      out[(size_t)(x0 + ty + j) * EDIM + (y0 + tx)] = f2bf(tile[tx][ty + j]);
  } else {
    const int idx = bid - 20480;
    const int bh = idx >> 8;
    const int tile16 = idx & 255;
    const int qt = tile16 >> 4, kt = tile16 & 15;
    const int r = t >> 1;
    const size_t base = ((size_t)bh * LQ + qt * 128 + r) * LQ + kt * 128 + (t & 1) * 64;
    const uint4* p = (const uint4*)(mask + base);
    uint4 a = p[0], c = p[1], d = p[2], e = p[3];
    uint32_t any = a.x | a.y | a.z | a.w | c.x | c.y | c.z | c.w |
                   d.x | d.y | d.z | d.w | e.x | e.y | e.z | e.w;
    int wa = __any(any != 0);
    if ((t & 63) == 0) wany[t >> 6] = wa;
    __syncthreads();
    if (t == 0)
      flags[(size_t)bh * 256 + tile16] = (unsigned char)(wany[0] | wany[1] | wany[2] | wany[3]);
  }
}

// ---------------- BK=64 GEMM core (XOR-swizzled LDS, 128x128 tile) ----------------
struct GemmCore {
  template <typename EpiF>
  static __device__ __forceinline__ void run(const u16* __restrict__ A, const u16* __restrict__ Bt,
                                             int m0, int n0, u16* As, u16* Bs, EpiF epi) {
    const int tid = threadIdx.x;
    const int l = tid & 63;
    const int w = tid >> 6;
    const int wm = (w >> 1) * 64;
    const int wn = (w & 1) * 64;
    const int fm = l & 15;
    const int q4 = l >> 4;
    const int f7 = fm & 7;
    f32x4 acc[4][4] = {};
    for (int k0 = 0; k0 < EDIM; k0 += 64) {
      __syncthreads();
#pragma unroll
      for (int ii = 0; ii < 4; ++ii) {
        const int rloc = w * 32 + ii * 8 + (l >> 3);
        const int cs = (l & 7) ^ (rloc & 7);
        async16(A + (size_t)(m0 + rloc) * EDIM + k0 + cs * 8, &As[(w * 32 + ii * 8) * 64 + l * 8]);
        async16(Bt + (size_t)(n0 + rloc) * EDIM + k0 + cs * 8, &Bs[(w * 32 + ii * 8) * 64 + l * 8]);
      }
      __syncthreads();
#pragma unroll
      for (int ks = 0; ks < 2; ++ks) {
        const int coff = ((ks * 4 + q4) ^ f7) * 8;
        bf16x8 a[4], b[4];
#pragma unroll
        for (int i = 0; i < 4; ++i) a[i] = *(const bf16x8*)&As[(wm + i * 16 + fm) * 64 + coff];
#pragma unroll
        for (int j = 0; j < 4; ++j) b[j] = *(const bf16x8*)&Bs[(wn + j * 16 + fm) * 64 + coff];
#pragma unroll
        for (int i = 0; i < 4; ++i)
#pragma unroll
          for (int j = 0; j < 4; ++j)
            acc[i][j] = __builtin_amdgcn_mfma_f32_16x16x32_bf16(a[i], b[j], acc[i][j], 0, 0, 0);
      }
    }
    const int rr = q4 * 4;
#pragma unroll
    for (int i = 0; i < 4; ++i)
#pragma unroll
      for (int j = 0; j < 4; ++j)
#pragma unroll
        for (int r = 0; r < 4; ++r)
          epi(m0 + wm + i * 16 + rr + r, n0 + wn + j * 16 + fm, acc[i][j][r]);
  }
};

__global__ __launch_bounds__(256) void qkv_gemm(const u16* __restrict__ xq, const u16* __restrict__ xkv,
                                                const u16* __restrict__ WqT, const u16* __restrict__ WkT,
                                                const u16* __restrict__ WvT,
                                                u16* __restrict__ Qb, u16* __restrict__ Kb,
                                                u16* __restrict__ Vt) {
  __shared__ __align__(16) u16 As[128 * 64];
  __shared__ __align__(16) u16 Bs[128 * 64];
  const int z = blockIdx.z;
  if (z == 0) {
    GemmCore::run(xq, WqT, blockIdx.x * 128, blockIdx.y * 128, As, Bs,
                  [&](int gm, int gn, float v) { Qb[(size_t)gm * EDIM + gn] = f2bf(v); });
  } else if (z == 1) {
    GemmCore::run(xkv, WkT, blockIdx.x * 128, blockIdx.y * 128, As, Bs,
                  [&](int gm, int gn, float v) { Kb[(size_t)gm * EDIM + gn] = f2bf(v); });
  } else {
    GemmCore::run(WvT, xkv, blockIdx.y * 128, blockIdx.x * 128, As, Bs,
                  [&](int gm, int gn, float v) {
                    Vt[((size_t)(gn >> 11) * 1024 + gm) * 2048 + (gn & 2047)] = f2bf(v);
                  });
  }
}

__global__ __launch_bounds__(256) void out_gemm(const u16* __restrict__ ctx, const u16* __restrict__ WfcT,
                                                float* __restrict__ out) {
  __shared__ __align__(16) u16 As[128 * 64];
  __shared__ __align__(16) u16 Bs[128 * 64];
  GemmCore::run(ctx, WfcT, blockIdx.x * 128, blockIdx.y * 128, As, Bs,
                [&](int gm, int gn, float v) { out[(size_t)gm * EDIM + gn] = v; });
}

// ---------------- flash attention v5: R7's v3 structure + MFMA row-sums ----------------
// grid (qtile=16, h=8, b=4); 4 waves x 32 q-rows; BN=64, K/V double-buffered, 1 barrier/iter.
// Softmax row-sum computed by an all-ones B-fragment MFMA (D[m][n] = sum_k P[m][k]):
// removes ALL per-iter shuffle reductions and scalar sums from the VALU path.
// lsum derives from the same bf16-quantized P used for O -> quantization cancels in O/lsum.
__global__ __launch_bounds__(256, 2) void attn_kernel(const u16* __restrict__ Qb, const u16* __restrict__ Kb,
                                                      const u16* __restrict__ Vt,
                                                      const unsigned char* __restrict__ mask,
                                                      const unsigned char* __restrict__ flags,
                                                      u16* __restrict__ ctx) {
  __shared__ __align__(16) u16 Ktile[2][64 * 128];   // [key][d] rows 256B = 16 chunks, XOR-swizzled
  __shared__ __align__(16) u16 Vtile[2][128 * 64];   // [d][key] rows 128B = 8 chunks, XOR-swizzled
  __shared__ __align__(16) u16 P[4 * 32 * 64];       // wave-private [32 q][64 key], XOR-swizzled
  const int tid = threadIdx.x;
  const int l = tid & 63;
  const int w = tid >> 6;
  const int qt = blockIdx.x;
  const int h = blockIdx.y;
  const int b = blockIdx.z;
  const int fm = l & 15;
  const int q4 = l >> 4;
  const int fk = q4 * 8;
  const int f7 = fm & 7;
  const int qbase = qt * 128 + w * 32;
  const int bh = b * HN + h;
  u16* Pw = &P[w * 2048];

  const u16* Kbh = Kb + (size_t)b * LQ * EDIM + h * DH;
  const u16* Vth = Vt + (size_t)bh * DH * LQ;
  const size_t mbase = (size_t)bh * (size_t)LQ * LQ;

  // per-qtile mask flags -> 16-bit mask (one bit per 128-key tile), loaded once
  const unsigned char* tf = flags + (size_t)bh * 256 + qt * 16;
  uint32_t fmask = 0;
#pragma unroll
  for (int i = 0; i < 16; ++i) fmask |= (tf[i] ? 1u : 0u) << i;

  // Q fragments
  bf16x8 qf[2][4];
#pragma unroll
  for (int mt = 0; mt < 2; ++mt)
#pragma unroll
    for (int ks = 0; ks < 4; ++ks)
      qf[mt][ks] = *(const bf16x8*)(Qb + (size_t)(b * LQ + qbase + mt * 16 + fm) * EDIM + h * DH + ks * 32 + fk);

  auto stageK = [&](int kt_, int buf) {
#pragma unroll
    for (int ii = 0; ii < 4; ++ii) {
      const int i = w * 4 + ii;
      const int row = i * 4 + (l >> 4);
      const int g = (l & 15) ^ (row & 7);
      async16(Kbh + (size_t)(kt_ * 64 + row) * EDIM + g * 8, &Ktile[buf][i * 512 + l * 8]);
    }
  };
  auto stageV = [&](int kt_, int buf) {
#pragma unroll
    for (int ii = 0; ii < 4; ++ii) {
      const int i = w * 4 + ii;
      const int row = i * 8 + (l >> 3);
      const int g = (l & 7) ^ (row & 7);
      async16(Vth + (size_t)row * LQ + kt_ * 64 + g * 8, &Vtile[buf][i * 512 + l * 8]);
    }
  };

  stageK(0, 0);
  stageV(0, 0);

  // all-ones bf16 B-fragment (1.0 = 0x3F80) for MFMA row-sums
  const bf16x8 ones = {0x3F80, 0x3F80, 0x3F80, 0x3F80, 0x3F80, 0x3F80, 0x3F80, 0x3F80};

  f32x4 o[2][8] = {};
  f32x4 ls[2] = {};   // row-sum accumulators (every column n holds the same value)

  for (int kt = 0; kt < 32; ++kt) {
    const int cur = kt & 1;
    __syncthreads();  // drains own K/V(kt) DMA (issued a full iter ago) + buffer handoff
    if (kt + 1 < 32) { stageK(kt + 1, 1 - cur); stageV(kt + 1, 1 - cur); }

    const u16* KT = &Ktile[cur][0];
    const u16* VT = &Vtile[cur][0];

    // ---- S = Q K^T
    f32x4 s[2][4] = {};
#pragma unroll
    for (int ks = 0; ks < 4; ++ks) {
      const int slot = (ks * 4 + q4) ^ f7;
      bf16x8 kf0, kf1, kf2, kf3;
      ldsr4(kf0, kf1, kf2, kf3,
            lds_b(KT + (0 * 16 + fm) * 128 + slot * 8),
            lds_b(KT + (1 * 16 + fm) * 128 + slot * 8),
            lds_b(KT + (2 * 16 + fm) * 128 + slot * 8),
            lds_b(KT + (3 * 16 + fm) * 128 + slot * 8));
#pragma unroll
      for (int mt = 0; mt < 2; ++mt) {
        s[mt][0] = __builtin_amdgcn_mfma_f32_16x16x32_bf16(qf[mt][ks], kf0, s[mt][0], 0, 0, 0);
        s[mt][1] = __builtin_amdgcn_mfma_f32_16x16x32_bf16(qf[mt][ks], kf1, s[mt][1], 0, 0, 0);
        s[mt][2] = __builtin_amdgcn_mfma_f32_16x16x32_bf16(qf[mt][ks], kf2, s[mt][2], 0, 0, 0);
        s[mt][3] = __builtin_amdgcn_mfma_f32_16x16x32_bf16(qf[mt][ks], kf3, s[mt][3], 0, 0, 0);
      }
    }

    // ---- exp (no max-subtraction; masked -> 0). No sums/shuffles here (MFMA does the sum).
    const int hasMask = (fmask >> (kt >> 1)) & 1;
    if (hasMask) {
#pragma unroll
      for (int mt = 0; mt < 2; ++mt)
#pragma unroll
        for (int r = 0; r < 4; ++r) {
          const int qr = qbase + mt * 16 + q4 * 4 + r;
          const unsigned char* mrow = mask + mbase + (size_t)qr * LQ + kt * 64 + fm;
#pragma unroll
          for (int nt = 0; nt < 4; ++nt)
            s[mt][nt][r] = mrow[nt * 16] ? 0.f : exp2f(s[mt][nt][r] * SCALE_LOG2E);
        }
    } else {
#pragma unroll
      for (int mt = 0; mt < 2; ++mt)
#pragma unroll
        for (int nt = 0; nt < 4; ++nt)
#pragma unroll
          for (int r = 0; r < 4; ++r)
            s[mt][nt][r] = exp2f(s[mt][nt][r] * SCALE_LOG2E);
    }

    // ---- P to wave-private LDS (packed cvt, b16 asm writes; swizzled)
#pragma unroll
    for (int mt = 0; mt < 2; ++mt)
#pragma unroll
      for (int r = 0; r < 4; ++r) {
        const int ql = mt * 16 + q4 * 4 + r;
        const uint32_t base = lds_b(Pw + ql * 64 + (fm & 7));
#pragma unroll
        for (int np = 0; np < 2; ++np) {
          uint32_t pk = pk2bf(s[mt][2 * np][r], s[mt][2 * np + 1][r]);
          const int c0 = (2 * (2 * np) + (fm >> 3)) ^ (ql & 7);
          const int c1 = (2 * (2 * np + 1) + (fm >> 3)) ^ (ql & 7);
          ldsw16(base + c0 * 16, (u16)pk);
          ldsw16(base + c1 * 16, (u16)(pk >> 16));
        }
      }
    lgkm_drain();  // P writes visible before P reads issue

    // ---- O += P V  (+ row-sum via all-ones B fragment)
#pragma unroll
    for (int ns = 0; ns < 2; ++ns) {
      const int pslot = (4 * ns + q4) ^ f7;
      bf16x8 pf0, pf1;
      ldsr2(pf0, pf1, lds_b(Pw + fm * 64 + pslot * 8), lds_b(Pw + (16 + fm) * 64 + pslot * 8));
      ls[0] = __builtin_amdgcn_mfma_f32_16x16x32_bf16(pf0, ones, ls[0], 0, 0, 0);
      ls[1] = __builtin_amdgcn_mfma_f32_16x16x32_bf16(pf1, ones, ls[1], 0, 0, 0);
      const int vslot = (4 * ns + q4) ^ f7;
      bf16x8 v0, v1, v2, v3, v4, v5, v6, v7;
      ldsr4(v0, v1, v2, v3,
            lds_b(VT + (0 * 16 + fm) * 64 + vslot * 8), lds_b(VT + (1 * 16 + fm) * 64 + vslot * 8),
            lds_b(VT + (2 * 16 + fm) * 64 + vslot * 8), lds_b(VT + (3 * 16 + fm) * 64 + vslot * 8));
      ldsr4(v4, v5, v6, v7,
            lds_b(VT + (4 * 16 + fm) * 64 + vslot * 8), lds_b(VT + (5 * 16 + fm) * 64 + vslot * 8),
            lds_b(VT + (6 * 16 + fm) * 64 + vslot * 8), lds_b(VT + (7 * 16 + fm) * 64 + vslot * 8));
      o[0][0] = __builtin_amdgcn_mfma_f32_16x16x32_bf16(pf0, v0, o[0][0], 0, 0, 0);
      o[1][0] = __builtin_amdgcn_mfma_f32_16x16x32_bf16(pf1, v0, o[1][0], 0, 0, 0);
      o[0][1] = __builtin_amdgcn_mfma_f32_16x16x32_bf16(pf0, v1, o[0][1], 0, 0, 0);
      o[1][1] = __builtin_amdgcn_mfma_f32_16x16x32_bf16(pf1, v1, o[1][1], 0, 0, 0);
      o[0][2] = __builtin_amdgcn_mfma_f32_16x16x32_bf16(pf0, v2, o[0][2], 0, 0, 0);
      o[1][2] = __builtin_amdgcn_mfma_f32_16x16x32_bf16(pf1, v2, o[1][2], 0, 0, 0);
      o[0][3] = __builtin_amdgcn_mfma_f32_16x16x32_bf16(pf0, v3, o[0][3], 0, 0, 0);
      o[1][3] = __builtin_amdgcn_mfma_f32_16x16x32_bf16(pf1, v3, o[1][3], 0, 0, 0);
      o[0][4] = __builtin_amdgcn_mfma_f32_16x16x32_bf16(pf0, v4, o[0][4], 0, 0, 0);
      o[1][4] = __builtin_amdgcn_mfma_f32_16x16x32_bf16(pf1, v4, o[1][4], 0, 0, 0);
      o[0][5] = __builtin_amdgcn_mfma_f32_16x16x32_bf16(pf0, v5, o[0][5], 0, 0, 0);
      o[1][5] = __builtin_amdgcn_mfma_f32_16x16x32_bf16(pf1, v5, o[1][5], 0, 0, 0);
      o[0][6] = __builtin_amdgcn_mfma_f32_16x16x32_bf16(pf0, v6, o[0][6], 0, 0, 0);
      o[1][6] = __builtin_amdgcn_mfma_f32_16x16x32_bf16(pf1, v6, o[1][6], 0, 0, 0);
      o[0][7] = __builtin_amdgcn_mfma_f32_16x16x32_bf16(pf0, v7, o[0][7], 0, 0, 0);
      o[1][7] = __builtin_amdgcn_mfma_f32_16x16x32_bf16(pf1, v7, o[1][7], 0, 0, 0);
    }
  }

  // ---- epilogue: ctx = O / lsum  (ls[mt][r] holds the row sum, identical across n)
#pragma unroll
  for (int mt = 0; mt < 2; ++mt)
#pragma unroll
    for (int r = 0; r < 4; ++r) {
      float inv = 1.f / ls[mt][r];
      int gq = b * LQ + qbase + mt * 16 + q4 * 4 + r;
#pragma unroll
      for (int dt = 0; dt < 8; ++dt)
        ctx[(size_t)gq * EDIM + h * DH + dt * 16 + fm] = f2bf(o[mt][dt][r] * inv);
    }
}

extern "C" void kernel_launch(void* const* d_in, const int* in_sizes, int n_in,
                              void* d_out, int out_size, void* d_ws, size_t ws_size,
                              hipStream_t stream) {
  const float* qIn = (const float*)d_in[0];
  const float* kvIn = (const float*)d_in[1];
  const unsigned char* mask = (const unsigned char*)d_in[2];
  const float* W_Q = (const float*)d_in[3];
  const float* W_K = (const float*)d_in[4];
  const float* W_V = (const float*)d_in[5];
  const float* W_fc = (const float*)d_in[6];
  float* out = (float*)d_out;

  uint8_t* ws = (uint8_t*)d_ws;
  const size_t MB = 1u << 20;
  u16* xq   = (u16*)(ws);
  u16* xkv  = (u16*)(ws + 16 * MB);
  u16* WqT  = (u16*)(ws + 32 * MB);
  u16* WkT  = (u16*)(ws + 34 * MB);
  u16* WvT  = (u16*)(ws + 36 * MB);
  u16* WfcT = (u16*)(ws + 38 * MB);
  u16* Qb   = (u16*)(ws + 40 * MB);
  u16* Kb   = (u16*)(ws + 56 * MB);
  u16* Vt   = (u16*)(ws + 72 * MB);
  u16* ctx  = (u16*)(ws + 88 * MB);
  unsigned char* flags = (unsigned char*)(ws + 104 * MB);

  prep_kernel<<<28672, 256, 0, stream>>>(qIn, kvIn, W_Q, W_K, W_V, W_fc, mask,
                                         xq, xkv, WqT, WkT, WvT, WfcT, flags);
  qkv_gemm<<<dim3(64, 8, 3), 256, 0, stream>>>(xq, xkv, WqT, WkT, WvT, Qb, Kb, Vt);
  attn_kernel<<<dim3(16, 8, 4), 256, 0, stream>>>(Qb, Kb, Vt, mask, flags, ctx);
  out_gemm<<<dim3(64, 8), 256, 0, stream>>>(ctx, WfcT, out);
}